// Round 1
// baseline (161.968 us; speedup 1.0000x reference)
//
#include <hip/hip_runtime.h>
#include <math.h>

#define BB 1024
#define S 32
#define DIM 64
#define NREL 237
#define NENT 14541
#define SIGMA 0.1f

// ---- workspace layout (float offsets) ----
#define OFS_WR    0                       // 238*64  : Wr = relf_ext @ W_agg0 (row 237 = 0)
#define N_WR      (238*64)
#define OFS_WC0   15232                   // 64*237  : W_agg1 @ W_out[:237]
#define N_WC      (64*237)
#define OFS_WC1   (OFS_WC0 + N_WC)        // 64*237
#define OFS_BC    (OFS_WC1 + N_WC)        // 237
#define OFS_A     45872                   // 14542*64 : per-entity aggregate (float4-aligned)
#define OFS_WM    976560                  // 64*64   : Wm = W_agg1 @ mW1[:237]
#define OFS_PE    980656                  // 1024*64 : pre_eps[b] = (b1 + sigma*eps_b)@mW1[:237] + mb1

// gf LDS map (floats):
//   s_v1   [0,4352)      2 units x 32 j x 68
//   s_r1   [4352,4416)   int
//   s_ent2 [4416,4480)   int
//   s_m1   [4480,4544)
//   s_ov   [4544,4672)   2 x 64 (persists into epilogue)
// epilogue aliases [0,1152): s_outp[0,480) s_vp[480,960) s_hA[960,1024)
//   s_hB[1024,1088) s_omix[1088,1152)
// total 4672 floats = 18688 B -> 4 blocks x 8 waves = 32 waves/CU (max).
#define LDS_BYTES 18688

__device__ __forceinline__ float selu_f(float x) {
    const float alpha = 1.6732632423543772f;
    const float scale = 1.0507009873554805f;
    return scale * (x > 0.f ? x : alpha * expm1f(x));
}

// ---------- Kernel 1: Wr only (everything downstream depends on this) ----------
__global__ __launch_bounds__(256) void pre_wr_kernel(
    const float* __restrict__ rel_feat, const float* __restrict__ W0,
    float* __restrict__ ws) {
    int idx = blockIdx.x * 256 + threadIdx.x;
    if (idx < 238 * 64) {
        int r = idx >> 6, o = idx & 63;
        float acc = 0.f;
        if (r < NREL) {
#pragma unroll 8
            for (int d = 0; d < 64; ++d)
                acc += rel_feat[r * 64 + d] * W0[d * 64 + o];
        }
        ws[OFS_WR + idx] = acc;            // row 237 stays 0
    }
}

// ---------- Kernel 2 (fused): agg (L2-gather-bound) + Wc/bc/Wm/pre_eps (FMA-bound) ----------
// The FMA-bound blocks are independent of the agg gather chain and co-schedule
// on the same CUs: latency of one hides under compute of the other.
__global__ __launch_bounds__(512) void mid_kernel(
    const int* __restrict__ e2e_tab, const int* __restrict__ e2r,
    const float* __restrict__ W1, const float* __restrict__ b1,
    const float* __restrict__ W_out, const float* __restrict__ b_out,
    const float* __restrict__ mW1, const float* __restrict__ mb1,
    const float* __restrict__ eps,
    float* __restrict__ ws) {
    __shared__ int   s_r[1024];
    __shared__ float red[512];
    int blk = blockIdx.x;
    const int tid = threadIdx.x;

    if (blk < 455) {                       // agg: 32 entities per block
        const int grp = tid >> 4, c = tid & 15;
        const int ent = blk * 32 + grp;
        const bool ok = ent < (NENT + 1);
        if (ok) {
            int ea = e2e_tab[ent * S + c];
            int eb = e2e_tab[ent * S + 16 + c];
            s_r[grp * 32 + c] = e2r[ea];
            s_r[grp * 32 + 16 + c] = e2r[eb];
        }
        __syncthreads();
        if (ok) {
            const float4* Wr4 = (const float4*)(ws + OFS_WR);
            const int* rr = &s_r[grp * 32];
            float4 acc = make_float4(0.f, 0.f, 0.f, 0.f);
#pragma unroll
            for (int s = 0; s < 32; ++s) {
                float4 v = Wr4[rr[s] * 16 + c];
                acc.x += v.x; acc.y += v.y; acc.z += v.z; acc.w += v.w;
            }
            ((float4*)(ws + OFS_A))[ent * 16 + c] = acc;
        }
        return;
    }
    blk -= 455;
    if (blk < 512) {                       // Wc0/Wc1: 8-way k-split (chain ~30)
        int half = blk >> 8;
        int lb = blk & 255;
        int o = lb >> 2, ct = lb & 3;
        int cl = tid & 63, q = tid >> 6;
        int c = ct * 64 + cl;
        const float* Wsrc = W_out + half * 237 * 237;
        float acc = 0.f;
        if (c < NREL) {
            int k0 = q * 30, k1 = (q == 7) ? 237 : (k0 + 30);
#pragma unroll 4
            for (int k = k0; k < k1; ++k)
                acc += W1[o * 237 + k] * Wsrc[k * 237 + c];
        }
        red[tid] = acc;
        __syncthreads();
        if (q == 0 && c < NREL) {
            float s = 0.f;
#pragma unroll
            for (int qq = 0; qq < 8; ++qq) s += red[qq * 64 + cl];
            ws[(half ? OFS_WC1 : OFS_WC0) + o * 237 + c] = s;
        }
        return;
    }
    blk -= 512;
    if (blk < 4) {                         // bc[c]
        int cl = tid & 63, q = tid >> 6;
        int c = blk * 64 + cl;
        float acc = 0.f;
        if (c < NREL) {
            int k0 = q * 30, k1 = (q == 7) ? 237 : (k0 + 30);
#pragma unroll 4
            for (int k = k0; k < k1; ++k)
                acc += b1[k] * (W_out[k * 237 + c] + W_out[(237 + k) * 237 + c]);
        }
        red[tid] = acc;
        __syncthreads();
        if (q == 0 && c < NREL) {
            float s = b_out[c];
#pragma unroll
            for (int qq = 0; qq < 8; ++qq) s += red[qq * 64 + cl];
            ws[OFS_BC + c] = s;
        }
        return;
    }
    blk -= 4;
    if (blk < 8) {                         // Wm = W1 @ mW1[:237]  (64x64)
        int idx = blk * 512 + tid;         // [0,4096)
        int o = idx >> 6, c = idx & 63;
        float acc = 0.f;
#pragma unroll 4
        for (int k = 0; k < 237; ++k)
            acc += W1[o * 237 + k] * mW1[k * 64 + c];
        ws[OFS_WM + idx] = acc;
        return;
    }
    blk -= 8;
    {                                      // pre_eps: 128 blocks x 8 b each
        int b = blk * 8 + (tid >> 6), w = tid & 63;
        const float* e = eps + b * 237;
        float acc = mb1[w];
#pragma unroll 4
        for (int k = 0; k < 237; ++k)
            acc += (SIGMA * e[k] + b1[k]) * mW1[k * 64 + w];
        ws[OFS_PE + b * 64 + w] = acc;
    }
}

// ---------- Kernel GF: gather-from-A + epilogue, 1 b per block, 512 threads ----------
__global__ __launch_bounds__(512, 8) void gf_kernel(
    const int* __restrict__ ep, const int* __restrict__ te_arr,
    const int* __restrict__ e2e_tab, const int* __restrict__ e2ent,
    const int* __restrict__ e2r, const float* __restrict__ b0,
    const float* __restrict__ t_arr,
    const float* __restrict__ mW1,
    const float* __restrict__ mW2, const float* __restrict__ mb2,
    const float* __restrict__ mW3, const float* __restrict__ mb3,
    const float* __restrict__ mW4, const float* __restrict__ mb4,
    const float* __restrict__ ws, float* __restrict__ out) {
    extern __shared__ float smem[];
    float* s_v1   = smem;                  // 2*32*68
    int*   s_r1   = (int*)(smem + 4352);
    int*   s_ent2 = (int*)(smem + 4416);
    float* s_m1   = smem + 4480;
    float* s_ov   = smem + 4544;

    const int tid = threadIdx.x;
    const int b = blockIdx.x;
    const int grp = tid >> 4;              // 32 groups of 16 threads
    const int c = tid & 15;
    const int te = te_arr[b];
    const int rte = e2r[te];
    const float4* Wr4 = (const float4*)(ws + OFS_WR);
    const float4* A4  = (const float4*)(ws + OFS_A);
    const float4 b0v  = ((const float4*)b0)[c];
    const float4 wrte = Wr4[rte * 16 + c];

    // stage-1 for both sides
    if (tid < 64) {
        int u = tid >> 5, s = tid & 31;
        int ent = ep[b * 2 + u];
        int e1 = e2e_tab[ent * S + s];
        s_r1[u * 32 + s] = e2r[e1];
        s_m1[u * 32 + s] = (e1 != te) ? 1.0f : 0.0f;
        s_ent2[u * 32 + s] = e2ent[e1];
    }
    __syncthreads();

    const float inv = 1.0f / 32.0f;
#pragma unroll
    for (int u = 0; u < 2; ++u) {
        const int j = grp;
        const int ent2 = s_ent2[u * 32 + j];
        int e2a = e2e_tab[ent2 * S + c];
        int e2b = e2e_tab[ent2 * S + 16 + c];
        int cnt = (e2a == te) + (e2b == te);
        cnt += __shfl_xor(cnt, 1);
        cnt += __shfl_xor(cnt, 2);
        cnt += __shfl_xor(cnt, 4);
        cnt += __shfl_xor(cnt, 8);
        float4 a4   = A4[ent2 * 16 + c];
        float4 self = Wr4[s_r1[u * 32 + j] * 16 + c];
        float fc = (float)cnt;
        float m = s_m1[u * 32 + j];
        float4 r;
        r.x = fmaxf(self.x + (a4.x - fc * wrte.x) * inv + b0v.x, 0.f) * m;
        r.y = fmaxf(self.y + (a4.y - fc * wrte.y) * inv + b0v.y, 0.f) * m;
        r.z = fmaxf(self.z + (a4.z - fc * wrte.z) * inv + b0v.z, 0.f) * m;
        r.w = fmaxf(self.w + (a4.w - fc * wrte.w) * inv + b0v.w, 0.f) * m;
        *((float4*)&s_v1[(u * 32 + j) * 68 + c * 4]) = r;
    }
    __syncthreads();
    if (tid < 128) {
        int u = tid >> 6, w = tid & 63;
        float sum = 0.f;
#pragma unroll 8
        for (int j = 0; j < 32; ++j) sum += s_v1[(u * 32 + j) * 68 + w];
        s_ov[u * 64 + w] = sum * inv;
    }
    __syncthreads();

    // ---------------- epilogue ----------------
    float* s_outp = smem;          // 2*240 : outv partials (K halves)
    float* s_vp   = smem + 480;    // 2*240 : vt partials
    float* s_hA   = smem + 960;    // 64
    float* s_hB   = smem + 1024;   // 64
    float* s_omix = smem + 1088;   // 64
    const float tb = t_arr[b];
    const float* Wc0 = ws + OFS_WC0;
    const float* Wc1 = ws + OFS_WC1;
    const float* bc  = ws + OFS_BC;
    const float* Wm  = ws + OFS_WM;
    const float* pe  = ws + OFS_PE + b * 64;

    // E1: omix (tid<64) + outv partials (K=128 split in 2 halves of 64)
    if (tid < 64)
        s_omix[tid] = (1.f - tb) * s_ov[tid] + tb * s_ov[64 + tid];
    {
        int half = tid >> 8, cc = tid & 255;
        if (cc < NREL) {
            const float* Wc  = half ? Wc1 : Wc0;
            const float* ovp = s_ov + half * 64;
            float a = 0.f;
#pragma unroll 4
            for (int d = 0; d < 64; ++d)
                a += ovp[d] * Wc[d * 237 + cc];
            s_outp[half * 240 + cc] = a;
        }
    }
    __syncthreads();

    // E2: h1 = selu(omix@Wm + pre_eps + t*mW1[237])   (64x64, folded)
    if (tid < 64) {
        float a0 = pe[tid] + tb * mW1[237 * 64 + tid];
        float a1 = 0.f, a2 = 0.f, a3 = 0.f;
#pragma unroll
        for (int d = 0; d < 64; d += 4) {
            a0 += s_omix[d]     * Wm[d * 64 + tid];
            a1 += s_omix[d + 1] * Wm[(d + 1) * 64 + tid];
            a2 += s_omix[d + 2] * Wm[(d + 2) * 64 + tid];
            a3 += s_omix[d + 3] * Wm[(d + 3) * 64 + tid];
        }
        s_hA[tid] = selu_f((a0 + a1) + (a2 + a3));
    }
    __syncthreads();

    // E3: h2
    if (tid < 64) {
        float a0 = mb2[tid], a1 = 0.f, a2 = 0.f, a3 = 0.f;
#pragma unroll
        for (int d = 0; d < 64; d += 4) {
            a0 += s_hA[d]     * mW2[d * 64 + tid];
            a1 += s_hA[d + 1] * mW2[(d + 1) * 64 + tid];
            a2 += s_hA[d + 2] * mW2[(d + 2) * 64 + tid];
            a3 += s_hA[d + 3] * mW2[(d + 3) * 64 + tid];
        }
        s_hB[tid] = selu_f((a0 + a1) + (a2 + a3));
    }
    __syncthreads();

    // E4: h3
    if (tid < 64) {
        float a0 = mb3[tid], a1 = 0.f, a2 = 0.f, a3 = 0.f;
#pragma unroll
        for (int d = 0; d < 64; d += 4) {
            a0 += s_hB[d]     * mW3[d * 64 + tid];
            a1 += s_hB[d + 1] * mW3[(d + 1) * 64 + tid];
            a2 += s_hB[d + 2] * mW3[(d + 2) * 64 + tid];
            a3 += s_hB[d + 3] * mW3[(d + 3) * 64 + tid];
        }
        s_hA[tid] = selu_f((a0 + a1) + (a2 + a3));
    }
    __syncthreads();

    // E5: vt partials (K=64 split in 2 halves of 32)
    {
        int half = tid >> 8, cc = tid & 255;
        if (cc < NREL) {
            float a = 0.f;
#pragma unroll 4
            for (int w = half * 32; w < half * 32 + 32; ++w)
                a += s_hA[w] * mW4[w * 237 + cc];
            s_vp[half * 240 + cc] = a;
        }
    }
    __syncthreads();

    // E6: final combine + store
    if (tid < NREL) {
        float outv = bc[tid] + s_outp[tid] + s_outp[240 + tid];
        out[b * 237 + tid] = outv * (mb4[tid] + s_vp[tid] + s_vp[240 + tid]);
    }
}

extern "C" void kernel_launch(void* const* d_in, const int* in_sizes, int n_in,
                              void* d_out, int out_size, void* d_ws, size_t ws_size,
                              hipStream_t stream) {
    const int* ep       = (const int*)d_in[0];
    const int* te       = (const int*)d_in[1];
    // d_in[2] = labels : dead code in the reference
    const int* e2e      = (const int*)d_in[3];
    const int* e2ent    = (const int*)d_in[4];
    const int* e2r      = (const int*)d_in[5];
    const float* t      = (const float*)d_in[6];
    const float* eps    = (const float*)d_in[7];
    const float* relf   = (const float*)d_in[8];
    const float* W0     = (const float*)d_in[9];
    const float* b0     = (const float*)d_in[10];
    const float* W1     = (const float*)d_in[11];
    const float* b1     = (const float*)d_in[12];
    const float* W_out  = (const float*)d_in[13];
    const float* b_out  = (const float*)d_in[14];
    const float* mW1    = (const float*)d_in[15];
    const float* mb1    = (const float*)d_in[16];
    const float* mW2    = (const float*)d_in[17];
    const float* mb2    = (const float*)d_in[18];
    const float* mW3    = (const float*)d_in[19];
    const float* mb3    = (const float*)d_in[20];
    const float* mW4    = (const float*)d_in[21];
    const float* mb4    = (const float*)d_in[22];
    float* ws  = (float*)d_ws;
    float* out = (float*)d_out;

    hipLaunchKernelGGL(pre_wr_kernel, dim3(60), dim3(256), 0, stream,
                       relf, W0, ws);
    hipLaunchKernelGGL(mid_kernel, dim3(1107), dim3(512), 0, stream,
                       e2e, e2r, W1, b1, W_out, b_out, mW1, mb1, eps, ws);
    hipLaunchKernelGGL(gf_kernel, dim3(BB), dim3(512), LDS_BYTES, stream,
                       ep, te, e2e, e2ent, e2r, b0,
                       t, mW1, mW2, mb2, mW3, mb3, mW4, mb4, ws, out);
}

// Round 2
// 137.564 us; speedup vs baseline: 1.1774x; 1.1774x over previous
//
#include <hip/hip_runtime.h>
#include <math.h>

#define BB 1024
#define S 32
#define DIM 64
#define NREL 237
#define NENT 14541
#define SIGMA 0.1f

// ---- workspace layout (float offsets) ----
#define OFS_WR    0                       // 238*64  : Wr = relf_ext @ W_agg0 (row 237 = 0)
#define N_WR      (238*64)
#define OFS_WC0   15232                   // 64*237  : W_agg1 @ W_out[:237]
#define N_WC      (64*237)
#define OFS_WC1   (OFS_WC0 + N_WC)        // 64*237
#define OFS_BC    (OFS_WC1 + N_WC)        // 237
#define OFS_A     45872                   // 14542*64 : per-entity aggregate (float4-aligned)
#define OFS_WM    976560                  // 64*64   : Wm = W_agg1 @ mW1[:237]
#define OFS_PE    980656                  // 1024*64 : pre_eps[b] = (b1 + sigma*eps_b)@mW1[:237] + mb1

// gf LDS map (floats):
//   s_v1   [0,4352)      2 units x 32 j x 68
//   s_r1   [4352,4416)   int
//   s_ent2 [4416,4480)   int
//   s_m1   [4480,4544)
//   s_ov   [4544,4672)   2 x 64 (persists into epilogue)
// epilogue aliases [0,1152): s_outp[0,480) s_vp[480,960) s_hA[960,1024)
//   s_hB[1024,1088) s_omix[1088,1152)
// total 4672 floats = 18688 B -> 4 blocks x 8 waves = 32 waves/CU (max).
#define LDS_BYTES 18688

__device__ __forceinline__ float selu_f(float x) {
    const float alpha = 1.6732632423543772f;
    const float scale = 1.0507009873554805f;
    return scale * (x > 0.f ? x : alpha * expm1f(x));
}

// ---------- Kernel 1 (fused pre): Wr + Wm + pre_eps ----------
// All three pieces depend only on raw inputs; the GPU is otherwise idle here.
// Wm/pre_eps stage their wave-uniform operands (W1 rows / eps rows / b1) into
// LDS via coalesced vector loads to avoid 237-deep scalar-load latency chains.
__global__ __launch_bounds__(512) void pre_kernel(
    const float* __restrict__ rel_feat, const float* __restrict__ W0,
    const float* __restrict__ W1, const float* __restrict__ mW1,
    const float* __restrict__ b1, const float* __restrict__ mb1,
    const float* __restrict__ eps,
    float* __restrict__ ws) {
    __shared__ float sm[2160];             // 8*237 staged rows + 240 for b1
    int blk = blockIdx.x;
    const int tid = threadIdx.x;

    if (blk < 30) {                        // Wr: 238*64 outputs
        int idx = blk * 512 + tid;
        if (idx < 238 * 64) {
            int r = idx >> 6, o = idx & 63;
            float acc = 0.f;
            if (r < NREL) {
#pragma unroll 8
                for (int d = 0; d < 64; ++d)
                    acc += rel_feat[r * 64 + d] * W0[d * 64 + o];
            }
            ws[OFS_WR + idx] = acc;        // row 237 stays 0
        }
        return;
    }
    blk -= 30;
    if (blk < 8) {                         // Wm = W1 @ mW1[:237], 8 rows (o) per block
        int o0 = blk * 8;
        const float* src = W1 + o0 * 237;
        for (int i = tid; i < 8 * 237; i += 512) sm[i] = src[i];
        __syncthreads();
        int w = tid >> 6, cl = tid & 63;   // wave w owns row o0+w
        const float* row = sm + w * 237;
        float a0 = 0.f, a1 = 0.f, a2 = 0.f, a3 = 0.f;
#pragma unroll
        for (int k = 0; k < 236; k += 4) {
            a0 += row[k]     * mW1[k * 64 + cl];
            a1 += row[k + 1] * mW1[(k + 1) * 64 + cl];
            a2 += row[k + 2] * mW1[(k + 2) * 64 + cl];
            a3 += row[k + 3] * mW1[(k + 3) * 64 + cl];
        }
        a0 += row[236] * mW1[236 * 64 + cl];
        ws[OFS_WM + (o0 + w) * 64 + cl] = (a0 + a1) + (a2 + a3);
        return;
    }
    blk -= 8;
    {                                      // pre_eps: 128 blocks x 8 b each
        int b0 = blk * 8;
        const float* esrc = eps + b0 * 237;
        for (int i = tid; i < 8 * 237; i += 512) sm[i] = esrc[i];
        for (int i = tid; i < 237; i += 512) sm[1920 + i] = b1[i];
        __syncthreads();
        int w = tid >> 6, cl = tid & 63;   // wave w owns b0+w
        const float* ew = sm + w * 237;
        const float* bb = sm + 1920;
        float a0 = mb1[cl], a1 = 0.f, a2 = 0.f, a3 = 0.f;
#pragma unroll
        for (int k = 0; k < 236; k += 4) {
            a0 += (SIGMA * ew[k]     + bb[k])     * mW1[k * 64 + cl];
            a1 += (SIGMA * ew[k + 1] + bb[k + 1]) * mW1[(k + 1) * 64 + cl];
            a2 += (SIGMA * ew[k + 2] + bb[k + 2]) * mW1[(k + 2) * 64 + cl];
            a3 += (SIGMA * ew[k + 3] + bb[k + 3]) * mW1[(k + 3) * 64 + cl];
        }
        a0 += (SIGMA * ew[236] + bb[236]) * mW1[236 * 64 + cl];
        ws[OFS_PE + (b0 + w) * 64 + cl] = (a0 + a1) + (a2 + a3);
    }
}

// ---------- Kernel 2 (fused): agg (L2-gather-bound) + Wc/bc (FMA-bound) ----------
// Reverted to the round-0 shape: the FMA blocks co-schedule under the agg
// gather latency; no tail blocks with long scalar chains.
__global__ __launch_bounds__(512) void mid_kernel(
    const int* __restrict__ e2e_tab, const int* __restrict__ e2r,
    const float* __restrict__ W1, const float* __restrict__ b1,
    const float* __restrict__ W_out, const float* __restrict__ b_out,
    float* __restrict__ ws) {
    __shared__ int   s_r[1024];
    __shared__ float red[512];
    int blk = blockIdx.x;
    const int tid = threadIdx.x;

    if (blk < 455) {                       // agg: 32 entities per block
        const int grp = tid >> 4, c = tid & 15;
        const int ent = blk * 32 + grp;
        const bool ok = ent < (NENT + 1);
        if (ok) {
            int ea = e2e_tab[ent * S + c];
            int eb = e2e_tab[ent * S + 16 + c];
            s_r[grp * 32 + c] = e2r[ea];
            s_r[grp * 32 + 16 + c] = e2r[eb];
        }
        __syncthreads();
        if (ok) {
            const float4* Wr4 = (const float4*)(ws + OFS_WR);
            const int* rr = &s_r[grp * 32];
            float4 acc = make_float4(0.f, 0.f, 0.f, 0.f);
#pragma unroll
            for (int s = 0; s < 32; ++s) {
                float4 v = Wr4[rr[s] * 16 + c];
                acc.x += v.x; acc.y += v.y; acc.z += v.z; acc.w += v.w;
            }
            ((float4*)(ws + OFS_A))[ent * 16 + c] = acc;
        }
        return;
    }
    blk -= 455;
    if (blk < 512) {                       // Wc0/Wc1: 8-way k-split (chain ~30)
        int half = blk >> 8;
        int lb = blk & 255;
        int o = lb >> 2, ct = lb & 3;
        int cl = tid & 63, q = tid >> 6;
        int c = ct * 64 + cl;
        const float* Wsrc = W_out + half * 237 * 237;
        float acc = 0.f;
        if (c < NREL) {
            int k0 = q * 30, k1 = (q == 7) ? 237 : (k0 + 30);
#pragma unroll 4
            for (int k = k0; k < k1; ++k)
                acc += W1[o * 237 + k] * Wsrc[k * 237 + c];
        }
        red[tid] = acc;
        __syncthreads();
        if (q == 0 && c < NREL) {
            float s = 0.f;
#pragma unroll
            for (int qq = 0; qq < 8; ++qq) s += red[qq * 64 + cl];
            ws[(half ? OFS_WC1 : OFS_WC0) + o * 237 + c] = s;
        }
        return;
    }
    blk -= 512;
    {                                      // bc[c]: 4 blocks
        int cl = tid & 63, q = tid >> 6;
        int c = blk * 64 + cl;
        float acc = 0.f;
        if (c < NREL) {
            int k0 = q * 30, k1 = (q == 7) ? 237 : (k0 + 30);
#pragma unroll 4
            for (int k = k0; k < k1; ++k)
                acc += b1[k] * (W_out[k * 237 + c] + W_out[(237 + k) * 237 + c]);
        }
        red[tid] = acc;
        __syncthreads();
        if (q == 0 && c < NREL) {
            float s = b_out[c];
#pragma unroll
            for (int qq = 0; qq < 8; ++qq) s += red[qq * 64 + cl];
            ws[OFS_BC + c] = s;
        }
    }
}

// ---------- Kernel GF: gather-from-A + epilogue, 1 b per block, 512 threads ----------
__global__ __launch_bounds__(512, 8) void gf_kernel(
    const int* __restrict__ ep, const int* __restrict__ te_arr,
    const int* __restrict__ e2e_tab, const int* __restrict__ e2ent,
    const int* __restrict__ e2r, const float* __restrict__ b0,
    const float* __restrict__ t_arr,
    const float* __restrict__ mW1,
    const float* __restrict__ mW2, const float* __restrict__ mb2,
    const float* __restrict__ mW3, const float* __restrict__ mb3,
    const float* __restrict__ mW4, const float* __restrict__ mb4,
    const float* __restrict__ ws, float* __restrict__ out) {
    extern __shared__ float smem[];
    float* s_v1   = smem;                  // 2*32*68
    int*   s_r1   = (int*)(smem + 4352);
    int*   s_ent2 = (int*)(smem + 4416);
    float* s_m1   = smem + 4480;
    float* s_ov   = smem + 4544;

    const int tid = threadIdx.x;
    const int b = blockIdx.x;
    const int grp = tid >> 4;              // 32 groups of 16 threads
    const int c = tid & 15;
    const int te = te_arr[b];
    const int rte = e2r[te];
    const float4* Wr4 = (const float4*)(ws + OFS_WR);
    const float4* A4  = (const float4*)(ws + OFS_A);
    const float4 b0v  = ((const float4*)b0)[c];
    const float4 wrte = Wr4[rte * 16 + c];

    // stage-1 for both sides
    if (tid < 64) {
        int u = tid >> 5, s = tid & 31;
        int ent = ep[b * 2 + u];
        int e1 = e2e_tab[ent * S + s];
        s_r1[u * 32 + s] = e2r[e1];
        s_m1[u * 32 + s] = (e1 != te) ? 1.0f : 0.0f;
        s_ent2[u * 32 + s] = e2ent[e1];
    }
    __syncthreads();

    const float inv = 1.0f / 32.0f;
#pragma unroll
    for (int u = 0; u < 2; ++u) {
        const int j = grp;
        const int ent2 = s_ent2[u * 32 + j];
        int e2a = e2e_tab[ent2 * S + c];
        int e2b = e2e_tab[ent2 * S + 16 + c];
        int cnt = (e2a == te) + (e2b == te);
        cnt += __shfl_xor(cnt, 1);
        cnt += __shfl_xor(cnt, 2);
        cnt += __shfl_xor(cnt, 4);
        cnt += __shfl_xor(cnt, 8);
        float4 a4   = A4[ent2 * 16 + c];
        float4 self = Wr4[s_r1[u * 32 + j] * 16 + c];
        float fc = (float)cnt;
        float m = s_m1[u * 32 + j];
        float4 r;
        r.x = fmaxf(self.x + (a4.x - fc * wrte.x) * inv + b0v.x, 0.f) * m;
        r.y = fmaxf(self.y + (a4.y - fc * wrte.y) * inv + b0v.y, 0.f) * m;
        r.z = fmaxf(self.z + (a4.z - fc * wrte.z) * inv + b0v.z, 0.f) * m;
        r.w = fmaxf(self.w + (a4.w - fc * wrte.w) * inv + b0v.w, 0.f) * m;
        *((float4*)&s_v1[(u * 32 + j) * 68 + c * 4]) = r;
    }
    __syncthreads();
    if (tid < 128) {
        int u = tid >> 6, w = tid & 63;
        float sum = 0.f;
#pragma unroll 8
        for (int j = 0; j < 32; ++j) sum += s_v1[(u * 32 + j) * 68 + w];
        s_ov[u * 64 + w] = sum * inv;
    }
    __syncthreads();

    // ---------------- epilogue ----------------
    float* s_outp = smem;          // 2*240 : outv partials (K halves)
    float* s_vp   = smem + 480;    // 2*240 : vt partials
    float* s_hA   = smem + 960;    // 64
    float* s_hB   = smem + 1024;   // 64
    float* s_omix = smem + 1088;   // 64
    const float tb = t_arr[b];
    const float* Wc0 = ws + OFS_WC0;
    const float* Wc1 = ws + OFS_WC1;
    const float* bc  = ws + OFS_BC;
    const float* Wm  = ws + OFS_WM;
    const float* pe  = ws + OFS_PE + b * 64;

    // E1: omix (tid<64) + outv partials (K=128 split in 2 halves of 64)
    if (tid < 64)
        s_omix[tid] = (1.f - tb) * s_ov[tid] + tb * s_ov[64 + tid];
    {
        int half = tid >> 8, cc = tid & 255;
        if (cc < NREL) {
            const float* Wc  = half ? Wc1 : Wc0;
            const float* ovp = s_ov + half * 64;
            float a = 0.f;
#pragma unroll 4
            for (int d = 0; d < 64; ++d)
                a += ovp[d] * Wc[d * 237 + cc];
            s_outp[half * 240 + cc] = a;
        }
    }
    __syncthreads();

    // E2: h1 = selu(omix@Wm + pre_eps + t*mW1[237])   (64x64, folded)
    if (tid < 64) {
        float a0 = pe[tid] + tb * mW1[237 * 64 + tid];
        float a1 = 0.f, a2 = 0.f, a3 = 0.f;
#pragma unroll
        for (int d = 0; d < 64; d += 4) {
            a0 += s_omix[d]     * Wm[d * 64 + tid];
            a1 += s_omix[d + 1] * Wm[(d + 1) * 64 + tid];
            a2 += s_omix[d + 2] * Wm[(d + 2) * 64 + tid];
            a3 += s_omix[d + 3] * Wm[(d + 3) * 64 + tid];
        }
        s_hA[tid] = selu_f((a0 + a1) + (a2 + a3));
    }
    __syncthreads();

    // E3: h2
    if (tid < 64) {
        float a0 = mb2[tid], a1 = 0.f, a2 = 0.f, a3 = 0.f;
#pragma unroll
        for (int d = 0; d < 64; d += 4) {
            a0 += s_hA[d]     * mW2[d * 64 + tid];
            a1 += s_hA[d + 1] * mW2[(d + 1) * 64 + tid];
            a2 += s_hA[d + 2] * mW2[(d + 2) * 64 + tid];
            a3 += s_hA[d + 3] * mW2[(d + 3) * 64 + tid];
        }
        s_hB[tid] = selu_f((a0 + a1) + (a2 + a3));
    }
    __syncthreads();

    // E4: h3
    if (tid < 64) {
        float a0 = mb3[tid], a1 = 0.f, a2 = 0.f, a3 = 0.f;
#pragma unroll
        for (int d = 0; d < 64; d += 4) {
            a0 += s_hB[d]     * mW3[d * 64 + tid];
            a1 += s_hB[d + 1] * mW3[(d + 1) * 64 + tid];
            a2 += s_hB[d + 2] * mW3[(d + 2) * 64 + tid];
            a3 += s_hB[d + 3] * mW3[(d + 3) * 64 + tid];
        }
        s_hA[tid] = selu_f((a0 + a1) + (a2 + a3));
    }
    __syncthreads();

    // E5: vt partials (K=64 split in 2 halves of 32)
    {
        int half = tid >> 8, cc = tid & 255;
        if (cc < NREL) {
            float a = 0.f;
#pragma unroll 4
            for (int w = half * 32; w < half * 32 + 32; ++w)
                a += s_hA[w] * mW4[w * 237 + cc];
            s_vp[half * 240 + cc] = a;
        }
    }
    __syncthreads();

    // E6: final combine + store
    if (tid < NREL) {
        float outv = bc[tid] + s_outp[tid] + s_outp[240 + tid];
        out[b * 237 + tid] = outv * (mb4[tid] + s_vp[tid] + s_vp[240 + tid]);
    }
}

extern "C" void kernel_launch(void* const* d_in, const int* in_sizes, int n_in,
                              void* d_out, int out_size, void* d_ws, size_t ws_size,
                              hipStream_t stream) {
    const int* ep       = (const int*)d_in[0];
    const int* te       = (const int*)d_in[1];
    // d_in[2] = labels : dead code in the reference
    const int* e2e      = (const int*)d_in[3];
    const int* e2ent    = (const int*)d_in[4];
    const int* e2r      = (const int*)d_in[5];
    const float* t      = (const float*)d_in[6];
    const float* eps    = (const float*)d_in[7];
    const float* relf   = (const float*)d_in[8];
    const float* W0     = (const float*)d_in[9];
    const float* b0     = (const float*)d_in[10];
    const float* W1     = (const float*)d_in[11];
    const float* b1     = (const float*)d_in[12];
    const float* W_out  = (const float*)d_in[13];
    const float* b_out  = (const float*)d_in[14];
    const float* mW1    = (const float*)d_in[15];
    const float* mb1    = (const float*)d_in[16];
    const float* mW2    = (const float*)d_in[17];
    const float* mb2    = (const float*)d_in[18];
    const float* mW3    = (const float*)d_in[19];
    const float* mb3    = (const float*)d_in[20];
    const float* mW4    = (const float*)d_in[21];
    const float* mb4    = (const float*)d_in[22];
    float* ws  = (float*)d_ws;
    float* out = (float*)d_out;

    hipLaunchKernelGGL(pre_kernel, dim3(166), dim3(512), 0, stream,
                       relf, W0, W1, mW1, b1, mb1, eps, ws);
    hipLaunchKernelGGL(mid_kernel, dim3(971), dim3(512), 0, stream,
                       e2e, e2r, W1, b1, W_out, b_out, ws);
    hipLaunchKernelGGL(gf_kernel, dim3(BB), dim3(512), LDS_BYTES, stream,
                       ep, te, e2e, e2ent, e2r, b0,
                       t, mW1, mW2, mb2, mW3, mb3, mW4, mb4, ws, out);
}